// Round 1
// 1207.328 us; speedup vs baseline: 1.2439x; 1.2439x over previous
//
#include <hip/hip_runtime.h>

// HQQLinear: out[b,s,o] = sum_i x[b,s,i] * W[o,i] + bias[o]
// R2: 256x256 8-phase GEMM (HK/m201-style schedule in plain HIP).
//   - BK=64, 8 waves (2Mx4N), 512 thr, 128 KiB LDS (2 dbuf x 2 half x 128x64 per op)
//   - counted s_waitcnt vmcnt(2) at phases 4/8 only (loads in flight across barriers)
//   - raw s_barrier (no vmcnt-draining __syncthreads in main loop)
//   - setprio(1) around each 16-MFMA quadrant cluster; sched_barrier(0) after
//   - chunk swizzle phys = logical ^ (row&7): linear gload_lds dest,
//     inverse-swizzled global SOURCE, swizzled ds_read -> conflict-free b128
//   - bijective XCD swizzle: 1376 blocks = 8 * 172
//
// Dims: M=8192, N=11008, K=4096. 32 x 43 tiles, 64 K-tiles, 32 iterations.

#define K_DIM 4096
#define N_DIM 11008
#define M_DIM 8192
#define NG 704512  // N_GROUPS = 4096*11008/64

#define BM 256
#define BN 256
#define BK 64
#define NKT 64  // K_DIM / BK
#define NIT 32  // NKT / 2

typedef __bf16 bf16;
typedef bf16 bf16x4 __attribute__((ext_vector_type(4)));
typedef bf16 bf16x8 __attribute__((ext_vector_type(8)));
typedef float f32x4 __attribute__((ext_vector_type(4)));

__device__ __forceinline__ void async_copy16(const void* g, void* l) {
  __builtin_amdgcn_global_load_lds(
      (const __attribute__((address_space(1))) void*)g,
      (__attribute__((address_space(3))) void*)l,
      16, 0, 0);
}

__device__ __forceinline__ void barrier_() {
  asm volatile("" ::: "memory");
  __builtin_amdgcn_s_barrier();
  asm volatile("" ::: "memory");
}
#define VMW(n) asm volatile("s_waitcnt vmcnt(" #n ")" ::: "memory")

// ---------------- x: fp32 -> bf16, 4 elems/thread ----------------
__global__ void cvt_x(const float* __restrict__ X, bf16* __restrict__ Xb) {
  const int idx = (blockIdx.x * 256 + threadIdx.x) * 4;
  const float4 v = *(const float4*)(X + idx);
  bf16x4 o;
  o[0] = (bf16)v.x; o[1] = (bf16)v.y; o[2] = (bf16)v.z; o[3] = (bf16)v.w;
  *(bf16x4*)(Xb + idx) = o;
}

// ---------------- W dequant: HQQ 4-bit -> bf16 [N][K] ----------------
__global__ void dequant_w(const int* __restrict__ Wq, const float* __restrict__ scale,
                          const float* __restrict__ zero, bf16* __restrict__ Wb) {
  const int idx = blockIdx.x * 256 + threadIdx.x;  // 32 * NG/4 threads
  const int r = idx / (NG / 4);                    // 0..31
  const int g = (idx - r * (NG / 4)) * 4;
  const int4 q = *(const int4*)(Wq + r * NG + g);
  const float4 sc = *(const float4*)(scale + g);
  const float4 zp = *(const float4*)(zero + g);
  const int c = g >> 12;    // g / 4096
  const int i = g & 4095;
  bf16x4 hi, lo;
  hi[0] = (bf16)(((float)((q.x >> 4) & 0xF) - zp.x) * sc.x);
  hi[1] = (bf16)(((float)((q.y >> 4) & 0xF) - zp.y) * sc.y);
  hi[2] = (bf16)(((float)((q.z >> 4) & 0xF) - zp.z) * sc.z);
  hi[3] = (bf16)(((float)((q.w >> 4) & 0xF) - zp.w) * sc.w);
  lo[0] = (bf16)(((float)(q.x & 0xF) - zp.x) * sc.x);
  lo[1] = (bf16)(((float)(q.y & 0xF) - zp.y) * sc.y);
  lo[2] = (bf16)(((float)(q.z & 0xF) - zp.z) * sc.z);
  lo[3] = (bf16)(((float)(q.w & 0xF) - zp.w) * sc.w);
  *(bf16x4*)(Wb + (size_t)(r * 172 + c) * 4096 + i) = hi;
  *(bf16x4*)(Wb + (size_t)((r + 32) * 172 + c) * 4096 + i) = lo;
}

// ---------------- GEMM: C[M][N] = A[M][K] * B[N][K]^T + bias ----------------
// LDS map (bytes): As half (b,h) at (b*2+h)*16384; Bs at 65536 + same.
// Within a half [128 rows][64 cols bf16]: row r at r*128, 16B chunk c at
// phys chunk c ^ (r&7)  (involution; staged via inverse-swizzled source).
//
// Schedule per iteration i (tiles T0=2i in buf0: P1-4, T1=2i+1 in buf1: P5-8).
// Half-tile units: u0=A-h0, u1=A-h1, u2=B-h0, u3=B-h1. Stages:
//   P1,P2,P3: (T1, u1,u2,u3) -> buf1   [buf1 reads retired since prev P7 barrier]
//   P4..P7:   (2i+2, u0..u3) -> buf0   [buf0 reads all issued by P3, retired at
//                                       P3 lgkmcnt, global by P3 post-barrier]
//   P8:       (2i+3, u0)     -> buf1
// vmcnt(2) at P4: 10 loads out -> oldest 8 (all of T1) landed, (2i+2,u0) in flight.
// vmcnt(2) at P8: 10 out -> all of tile 2i+2 landed, (2i+3,u0) in flight.
// Last iteration (it=31): stages for tiles>=64 skipped, P4 waits vmcnt(0).
__global__ __launch_bounds__(512, 2)
void gemm_bt(const bf16* __restrict__ A, const bf16* __restrict__ B,
             const float* __restrict__ bias, float* __restrict__ C) {
  extern __shared__ char smem[];

  const int tid = threadIdx.x;
  const int wave = tid >> 6;
  const int lane = tid & 63;
  const int l15 = lane & 15;
  const int quad = lane >> 4;
  const int wm = wave >> 2;  // 0..1 -> A half, 128 output rows
  const int wn = wave & 3;   // 0..3 -> 64 output cols

  // bijective XCD swizzle (1376 = 8*172), then m-fastest so consecutive
  // blocks on an XCD share the same B panel in its L2.
  const int id = blockIdx.x;
  const int wg = (id & 7) * 172 + (id >> 3);
  const int bm = (wg & 31) * BM;
  const int bn = (wg >> 5) * BN;

  // ---- staging constants (thread covers row srow, phys chunk tid&7) ----
  const int srow = tid >> 3;                    // 0..63 within a 64-row block
  const int qc = (tid & 7) ^ (srow & 7);        // inverse-swizzled logical chunk
  const bf16* sA = A + (size_t)(bm + srow) * K_DIM + qc * 8;
  const bf16* sB = B + (size_t)(bn + srow) * K_DIM + qc * 8;
  const int ldsWave = wave << 10;               // HW adds lane*16

  auto stageA = [&](int b, int h, int t) {
    const bf16* g = sA + (size_t)(h * 128) * K_DIM + (size_t)t * BK;
    char* l = smem + (b * 2 + h) * 16384 + ldsWave;
    async_copy16(g, l);
    async_copy16(g + (size_t)64 * K_DIM, l + 8192);
  };
  auto stageB = [&](int b, int h, int t) {
    const bf16* g = sB + (size_t)(h * 128) * K_DIM + (size_t)t * BK;
    char* l = smem + 65536 + (b * 2 + h) * 16384 + ldsWave;
    async_copy16(g, l);
    async_copy16(g + (size_t)64 * K_DIM, l + 8192);
  };

  // ---- fragment read offsets (row&7 == l15&7 for every fragment row) ----
  const int sw = l15 & 7;
  const int ro = l15 * 128;
  const int k0 = (quad ^ sw) << 4;          // ks=0 chunk byte offset
  const int k1 = ((quad + 4) ^ sw) << 4;    // ks=1
  const char* rdA0 = smem + wm * 16384 + ro;                               // buf0
  const char* rdB0 = smem + 65536 + (wn >> 1) * 16384 + (wn & 1) * 8192 + ro;

  auto ldA = [&](bf16x8 (&d)[4][2], const char* base, int fm) {
#pragma unroll
    for (int m = 0; m < 4; ++m) {
      const char* p = base + (fm + m) * 2048;
      d[m][0] = *(const bf16x8*)(p + k0);
      d[m][1] = *(const bf16x8*)(p + k1);
    }
  };
  auto ldB = [&](bf16x8 (&d)[2][2], const char* base, int gn) {
#pragma unroll
    for (int n = 0; n < 2; ++n) {
      const char* p = base + (gn + n) * 2048;
      d[n][0] = *(const bf16x8*)(p + k0);
      d[n][1] = *(const bf16x8*)(p + k1);
    }
  };

  f32x4 acc[8][4];
#pragma unroll
  for (int m = 0; m < 8; ++m)
#pragma unroll
    for (int n = 0; n < 4; ++n) {
      f32x4 z = {0.f, 0.f, 0.f, 0.f};
      acc[m][n] = z;
    }

  auto mmq = [&](bf16x8 (&a)[4][2], bf16x8 (&b)[2][2], int fm, int gn) {
    __builtin_amdgcn_s_setprio(1);
#pragma unroll
    for (int m = 0; m < 4; ++m)
#pragma unroll
      for (int n = 0; n < 2; ++n) {
        acc[fm + m][gn + n] = __builtin_amdgcn_mfma_f32_16x16x32_bf16(
            a[m][0], b[n][0], acc[fm + m][gn + n], 0, 0, 0);
        acc[fm + m][gn + n] = __builtin_amdgcn_mfma_f32_16x16x32_bf16(
            a[m][1], b[n][1], acc[fm + m][gn + n], 0, 0, 0);
      }
    __builtin_amdgcn_s_setprio(0);
    __builtin_amdgcn_sched_barrier(0);  // pin MFMAs (and their lgkm waits) here
  };

  // ---- prologue: tile0 (4 halves) -> buf0, tile1 u0 -> buf1 ----
  stageA(0, 0, 0); stageA(0, 1, 0); stageB(0, 0, 0); stageB(0, 1, 0);
  stageA(1, 0, 1);
  VMW(2);  // tile0 fully landed; (t1,u0) in flight
  barrier_();

  for (int it = 0; it < NIT; ++it) {
    const int t1 = 2 * it + 1, t2 = 2 * it + 2, t3 = 2 * it + 3;
    const bool more = (it < NIT - 1);
    bf16x8 a0[4][2], a1[4][2], p0[2][2], p1[2][2];

    // ---------- tile 2it from buf0 ----------
    // P1: Q(m0-3, n0-1)
    ldA(a0, rdA0, 0); ldB(p0, rdB0, 0);
    stageA(1, 1, t1);
    barrier_(); mmq(a0, p0, 0, 0); barrier_();
    // P2: Q(m0-3, n2-3)  (reuses a0)
    ldB(p1, rdB0, 2);
    stageB(1, 0, t1);
    barrier_(); mmq(a0, p1, 0, 2); barrier_();
    // P3: Q(m4-7, n0-1)  (reuses p0)
    ldA(a1, rdA0, 4);
    stageB(1, 1, t1);
    barrier_(); mmq(a1, p0, 4, 0); barrier_();
    // P4: Q(m4-7, n2-3)  (reuses a1, p1; no ds_reads)
    if (more) { stageA(0, 0, t2); VMW(2); } else { VMW(0); }
    barrier_(); mmq(a1, p1, 4, 2); barrier_();

    // ---------- tile 2it+1 from buf1 ----------
    const char* rA = rdA0 + 32768;
    const char* rB = rdB0 + 32768;
    // P5
    ldA(a0, rA, 0); ldB(p0, rB, 0);
    if (more) stageA(0, 1, t2);
    barrier_(); mmq(a0, p0, 0, 0); barrier_();
    // P6
    ldB(p1, rB, 2);
    if (more) stageB(0, 0, t2);
    barrier_(); mmq(a0, p1, 0, 2); barrier_();
    // P7
    ldA(a1, rA, 4);
    if (more) stageB(0, 1, t2);
    barrier_(); mmq(a1, p0, 4, 0); barrier_();
    // P8
    if (more) { stageA(1, 0, t3); VMW(2); }
    barrier_(); mmq(a1, p1, 4, 2); barrier_();
  }

  // ---- epilogue: C/D layout col=lane&15, row=quad*4+reg; nontemporal ----
  const int cm = bm + wm * 128 + quad * 4;
  const int cn = bn + wn * 64 + l15;
#pragma unroll
  for (int g = 0; g < 4; ++g) {
    const int col = cn + g * 16;
    const float bv = bias[col];
#pragma unroll
    for (int m = 0; m < 8; ++m) {
      float* cp = C + (size_t)(cm + m * 16) * N_DIM + col;
      const f32x4 a = acc[m][g];
      __builtin_nontemporal_store(a[0] + bv, cp + 0 * N_DIM);
      __builtin_nontemporal_store(a[1] + bv, cp + 1 * N_DIM);
      __builtin_nontemporal_store(a[2] + bv, cp + 2 * N_DIM);
      __builtin_nontemporal_store(a[3] + bv, cp + 3 * N_DIM);
    }
  }
}

extern "C" void kernel_launch(void* const* d_in, const int* in_sizes, int n_in,
                              void* d_out, int out_size, void* d_ws, size_t ws_size,
                              hipStream_t stream) {
  const float* x = (const float*)d_in[0];
  const int* Wq = (const int*)d_in[1];
  const float* scale = (const float*)d_in[2];
  const float* zero = (const float*)d_in[3];
  const float* bias = (const float*)d_in[4];
  float* out = (float*)d_out;

  bf16* Xb = (bf16*)d_ws;                              // 8192*4096*2 = 64 MiB
  bf16* Wb = (bf16*)((char*)d_ws + (size_t)67108864);  // 11008*4096*2 = 86 MiB

  static int smem_set = 0;
  if (!smem_set) {
    (void)hipFuncSetAttribute((const void*)gemm_bt,
                              hipFuncAttributeMaxDynamicSharedMemorySize, 131072);
    smem_set = 1;
  }

  cvt_x<<<32768, 256, 0, stream>>>(x, Xb);                    // 8192*4096/4/256
  dequant_w<<<22016, 256, 0, stream>>>(Wq, scale, zero, Wb);  // 32*(NG/4)/256
  gemm_bt<<<1376, 512, 131072, stream>>>(Xb, Wb, bias, out);  // 32*43 blocks
}

// Round 2
// 1069.634 us; speedup vs baseline: 1.4040x; 1.1287x over previous
//
#include <hip/hip_runtime.h>

// HQQLinear: out[b,s,o] = sum_i x[b,s,i] * W[o,i] + bias[o]
// R3: 256x256 8-phase GEMM with ds_read/MFMA overlap.
//   - Fragment reads issued INSIDE the previous phase's MFMA window
//     (DS pipe runs in parallel with MFMA pipe; compiler emits counted
//     lgkmcnt before the consuming MFMA cluster).
//   - Staging moved to slim pre-barrier windows; every staged unit has a
//     >=2-phase lead before its vmcnt; uniform VMW(4) at P4/P8.
//   - Keeps: chunk swizzle (phys = logical ^ (row&7), conflict-free b128),
//     bijective XCD swizzle (1376 = 8*172), setprio around MFMA clusters,
//     raw s_barrier (no vmcnt-draining __syncthreads in the main loop).
//
// Dims: M=8192, N=11008, K=4096. 32 x 43 tiles, 64 K-tiles, 32 iterations.

#define K_DIM 4096
#define N_DIM 11008
#define M_DIM 8192
#define NG 704512  // N_GROUPS = 4096*11008/64

#define BM 256
#define BN 256
#define BK 64
#define NKT 64  // K_DIM / BK
#define NIT 32  // NKT / 2

typedef __bf16 bf16;
typedef bf16 bf16x4 __attribute__((ext_vector_type(4)));
typedef bf16 bf16x8 __attribute__((ext_vector_type(8)));
typedef float f32x4 __attribute__((ext_vector_type(4)));

__device__ __forceinline__ void async_copy16(const void* g, void* l) {
  __builtin_amdgcn_global_load_lds(
      (const __attribute__((address_space(1))) void*)g,
      (__attribute__((address_space(3))) void*)l,
      16, 0, 0);
}

__device__ __forceinline__ void barrier_() {
  asm volatile("" ::: "memory");
  __builtin_amdgcn_s_barrier();
  asm volatile("" ::: "memory");
}
#define VMW(n) asm volatile("s_waitcnt vmcnt(" #n ")" ::: "memory")

// ---------------- x: fp32 -> bf16, 4 elems/thread ----------------
__global__ void cvt_x(const float* __restrict__ X, bf16* __restrict__ Xb) {
  const int idx = (blockIdx.x * 256 + threadIdx.x) * 4;
  const float4 v = *(const float4*)(X + idx);
  bf16x4 o;
  o[0] = (bf16)v.x; o[1] = (bf16)v.y; o[2] = (bf16)v.z; o[3] = (bf16)v.w;
  *(bf16x4*)(Xb + idx) = o;
}

// ---------------- W dequant: HQQ 4-bit -> bf16 [N][K] ----------------
__global__ void dequant_w(const int* __restrict__ Wq, const float* __restrict__ scale,
                          const float* __restrict__ zero, bf16* __restrict__ Wb) {
  const int idx = blockIdx.x * 256 + threadIdx.x;  // 32 * NG/4 threads
  const int r = idx / (NG / 4);                    // 0..31
  const int g = (idx - r * (NG / 4)) * 4;
  const int4 q = *(const int4*)(Wq + r * NG + g);
  const float4 sc = *(const float4*)(scale + g);
  const float4 zp = *(const float4*)(zero + g);
  const int c = g >> 12;    // g / 4096
  const int i = g & 4095;
  bf16x4 hi, lo;
  hi[0] = (bf16)(((float)((q.x >> 4) & 0xF) - zp.x) * sc.x);
  hi[1] = (bf16)(((float)((q.y >> 4) & 0xF) - zp.y) * sc.y);
  hi[2] = (bf16)(((float)((q.z >> 4) & 0xF) - zp.z) * sc.z);
  hi[3] = (bf16)(((float)((q.w >> 4) & 0xF) - zp.w) * sc.w);
  lo[0] = (bf16)(((float)(q.x & 0xF) - zp.x) * sc.x);
  lo[1] = (bf16)(((float)(q.y & 0xF) - zp.y) * sc.y);
  lo[2] = (bf16)(((float)(q.z & 0xF) - zp.z) * sc.z);
  lo[3] = (bf16)(((float)(q.w & 0xF) - zp.w) * sc.w);
  *(bf16x4*)(Wb + (size_t)(r * 172 + c) * 4096 + i) = hi;
  *(bf16x4*)(Wb + (size_t)((r + 32) * 172 + c) * 4096 + i) = lo;
}

// ---------------- GEMM: C[M][N] = A[M][K] * B[N][K]^T + bias ----------------
// LDS map (bytes): As half (b,h) at (b*2+h)*16384; Bs at 65536 + same.
// Row r at r*128; 16B chunk c at phys chunk c ^ (r&7).
//
// Per iteration i: T0=2i (buf0), T1=2i+1 (buf1), T2=2i+2, T3=2i+3.
// Quadrants per tile: Q00(a0,p0) Q01(a0,p1) Q10(a1,p0) Q11(a1,p1).
// Phase p = { [pre: stage unit; vmcnt?]; BAR; [post: next frag reads; MFMA]; BAR }
//   P1 pre: T1.u0(A-h0)   post: ld p1(T0);        mfma T0.Q00
//   P2 pre: T1.u1(A-h1)   post: ld a1(T0);        mfma T0.Q01
//   P3 pre: T2.u2(B-h0)   post: -;                mfma T0.Q10
//   P4 pre: T2.u3(B-h1), VMW(4)
//                         post: ld a0,p0(T1);     mfma T0.Q11
//   P5 pre: T2.u0         post: ld p1(T1);        mfma T1.Q00
//   P6 pre: T2.u1         post: ld a1(T1);        mfma T1.Q01
//   P7 pre: T3.u2         post: -;                mfma T1.Q10
//   P8 pre: T3.u3, VMW(4)
//                         post: ld a0,p0(T2,buf0); mfma T1.Q11
// WAR proofs (overwrite issued >=1 barrier after consuming lgkm-retirement):
//   T1.u0/u1 (buf1 A) @P1/P2: prev a1 reads retired before prev-P7 mfma,
//     block-safe after prev-P7 closing BAR (earliest prev-P8). OK.
//   T2.u2/u3 (buf0 B) @P3/P4: p1 reads retired before P2 mfma -> safe P3. OK.
//   T2.u0/u1 (buf0 A) @P5/P6: a1 reads retired before P3 mfma -> safe P4. OK.
//   T3.u2/u3 (buf1 B) @P7/P8: T1.p1 retired before P6 mfma -> safe P7. OK.
// RAW: VMW(4) queue at P4 = [T1.u2,u3,u0,u1,T2.u2,u3] (12 loads) -> retires
//   all of T1, leaves T2.u2/u3 in flight. Last T1 unit (u1@P2) has a
//   ~2-phase lead (~1200 cyc > 900 cyc HBM latency). Symmetric at P8.
// Last iteration: skip T2/T3 stages; P4 drains VMW(0); P8 skips reads.
__global__ __launch_bounds__(512, 2)
void gemm_bt(const bf16* __restrict__ A, const bf16* __restrict__ B,
             const float* __restrict__ bias, float* __restrict__ C) {
  extern __shared__ char smem[];

  const int tid = threadIdx.x;
  const int wave = tid >> 6;
  const int lane = tid & 63;
  const int l15 = lane & 15;
  const int quad = lane >> 4;
  const int wm = wave >> 2;  // 0..1 -> A half (128 output rows)
  const int wn = wave & 3;   // 0..3 -> 64 output cols

  // bijective XCD swizzle (1376 = 8*172), m-fastest within an XCD chunk.
  const int id = blockIdx.x;
  const int wg = (id & 7) * 172 + (id >> 3);
  const int bm = (wg & 31) * BM;
  const int bn = (wg >> 5) * BN;

  // ---- staging constants (thread covers row srow, phys chunk tid&7) ----
  const int srow = tid >> 3;                    // 0..63 within a 64-row block
  const int qc = (tid & 7) ^ (srow & 7);        // inverse-swizzled logical chunk
  const bf16* sA = A + (size_t)(bm + srow) * K_DIM + qc * 8;
  const bf16* sB = B + (size_t)(bn + srow) * K_DIM + qc * 8;
  const int ldsWave = wave << 10;               // HW adds lane*16

  auto stageA = [&](int b, int h, int t) {
    const bf16* g = sA + (size_t)(h * 128) * K_DIM + (size_t)t * BK;
    char* l = smem + (b * 2 + h) * 16384 + ldsWave;
    async_copy16(g, l);
    async_copy16(g + (size_t)64 * K_DIM, l + 8192);
  };
  auto stageB = [&](int b, int h, int t) {
    const bf16* g = sB + (size_t)(h * 128) * K_DIM + (size_t)t * BK;
    char* l = smem + 65536 + (b * 2 + h) * 16384 + ldsWave;
    async_copy16(g, l);
    async_copy16(g + (size_t)64 * K_DIM, l + 8192);
  };

  // ---- fragment read offsets ----
  const int sw = l15 & 7;
  const int ro = l15 * 128;
  const int k0 = (quad ^ sw) << 4;          // ks=0 chunk byte offset
  const int k1 = ((quad + 4) ^ sw) << 4;    // ks=1
  const char* rdA0 = smem + wm * 16384 + ro;
  const char* rdB0 = smem + 65536 + (wn >> 1) * 16384 + (wn & 1) * 8192 + ro;
  const char* rdA1 = rdA0 + 32768;
  const char* rdB1 = rdB0 + 32768;

  auto ldA = [&](bf16x8 (&d)[4][2], const char* base, int fm) {
#pragma unroll
    for (int m = 0; m < 4; ++m) {
      const char* p = base + (fm + m) * 2048;
      d[m][0] = *(const bf16x8*)(p + k0);
      d[m][1] = *(const bf16x8*)(p + k1);
    }
  };
  auto ldB = [&](bf16x8 (&d)[2][2], const char* base, int gn) {
#pragma unroll
    for (int n = 0; n < 2; ++n) {
      const char* p = base + (gn + n) * 2048;
      d[n][0] = *(const bf16x8*)(p + k0);
      d[n][1] = *(const bf16x8*)(p + k1);
    }
  };

  f32x4 acc[8][4];
#pragma unroll
  for (int m = 0; m < 8; ++m)
#pragma unroll
    for (int n = 0; n < 4; ++n) {
      f32x4 z = {0.f, 0.f, 0.f, 0.f};
      acc[m][n] = z;
    }

  auto mmq = [&](bf16x8 (&a)[4][2], bf16x8 (&b)[2][2], int fm, int gn) {
    __builtin_amdgcn_s_setprio(1);
#pragma unroll
    for (int m = 0; m < 4; ++m)
#pragma unroll
      for (int n = 0; n < 2; ++n) {
        acc[fm + m][gn + n] = __builtin_amdgcn_mfma_f32_16x16x32_bf16(
            a[m][0], b[n][0], acc[fm + m][gn + n], 0, 0, 0);
        acc[fm + m][gn + n] = __builtin_amdgcn_mfma_f32_16x16x32_bf16(
            a[m][1], b[n][1], acc[fm + m][gn + n], 0, 0, 0);
      }
    __builtin_amdgcn_s_setprio(0);
    __builtin_amdgcn_sched_barrier(0);  // keep this phase's work inside it
  };

  bf16x8 a0[4][2], a1[4][2], p0[2][2], p1[2][2];

  // ---- prologue: T0 (4 units -> buf0), T1.B (2 units -> buf1) ----
  stageB(0, 0, 0); stageB(0, 1, 0); stageA(0, 0, 0); stageA(0, 1, 0);
  stageB(1, 0, 1); stageB(1, 1, 1);
  VMW(4);  // T0 landed; T1.u2/u3 in flight
  barrier_();
  ldA(a0, rdA0, 0); ldB(p0, rdB0, 0);  // T0.Q00 fragments (exposed once)

  for (int it = 0; it < NIT; ++it) {
    const int t1 = 2 * it + 1, t2 = 2 * it + 2, t3 = 2 * it + 3;
    const bool more = (it < NIT - 1);

    // P1
    stageA(1, 0, t1);
    barrier_();
    ldB(p1, rdB0, 2);
    mmq(a0, p0, 0, 0);
    barrier_();
    // P2
    stageA(1, 1, t1);
    barrier_();
    ldA(a1, rdA0, 4);
    mmq(a0, p1, 0, 2);
    barrier_();
    // P3
    if (more) stageB(0, 0, t2);
    barrier_();
    mmq(a1, p0, 4, 0);
    barrier_();
    // P4
    if (more) { stageB(0, 1, t2); VMW(4); } else { VMW(0); }
    barrier_();
    ldA(a0, rdA1, 0); ldB(p0, rdB1, 0);  // T1.Q00
    mmq(a1, p1, 4, 2);
    barrier_();
    // P5
    if (more) stageA(0, 0, t2);
    barrier_();
    ldB(p1, rdB1, 2);
    mmq(a0, p0, 0, 0);
    barrier_();
    // P6
    if (more) stageA(0, 1, t2);
    barrier_();
    ldA(a1, rdA1, 4);
    mmq(a0, p1, 0, 2);
    barrier_();
    // P7
    if (more) stageB(1, 0, t3);
    barrier_();
    mmq(a1, p0, 4, 0);
    barrier_();
    // P8
    if (more) { stageB(1, 1, t3); VMW(4); }
    barrier_();
    if (more) { ldA(a0, rdA0, 0); ldB(p0, rdB0, 0); }  // T2.Q00 (buf0)
    mmq(a1, p1, 4, 2);
    barrier_();
  }

  // ---- epilogue: C/D layout col=lane&15, row=quad*4+reg; nontemporal ----
  const int cm = bm + wm * 128 + quad * 4;
  const int cn = bn + wn * 64 + l15;
#pragma unroll
  for (int g = 0; g < 4; ++g) {
    const int col = cn + g * 16;
    const float bv = bias[col];
#pragma unroll
    for (int m = 0; m < 8; ++m) {
      float* cp = C + (size_t)(cm + m * 16) * N_DIM + col;
      const f32x4 a = acc[m][g];
      __builtin_nontemporal_store(a[0] + bv, cp + 0 * N_DIM);
      __builtin_nontemporal_store(a[1] + bv, cp + 1 * N_DIM);
      __builtin_nontemporal_store(a[2] + bv, cp + 2 * N_DIM);
      __builtin_nontemporal_store(a[3] + bv, cp + 3 * N_DIM);
    }
  }
}

extern "C" void kernel_launch(void* const* d_in, const int* in_sizes, int n_in,
                              void* d_out, int out_size, void* d_ws, size_t ws_size,
                              hipStream_t stream) {
  const float* x = (const float*)d_in[0];
  const int* Wq = (const int*)d_in[1];
  const float* scale = (const float*)d_in[2];
  const float* zero = (const float*)d_in[3];
  const float* bias = (const float*)d_in[4];
  float* out = (float*)d_out;

  bf16* Xb = (bf16*)d_ws;                              // 8192*4096*2 = 64 MiB
  bf16* Wb = (bf16*)((char*)d_ws + (size_t)67108864);  // 11008*4096*2 = 86 MiB

  static int smem_set = 0;
  if (!smem_set) {
    (void)hipFuncSetAttribute((const void*)gemm_bt,
                              hipFuncAttributeMaxDynamicSharedMemorySize, 131072);
    smem_set = 1;
  }

  cvt_x<<<32768, 256, 0, stream>>>(x, Xb);                    // 8192*4096/4/256
  dequant_w<<<22016, 256, 0, stream>>>(Wq, scale, zero, Wb);  // 32*(NG/4)/256
  gemm_bt<<<1376, 512, 131072, stream>>>(Xb, Wb, bias, out);  // 32*43 blocks
}